// Round 7
// baseline (122.861 us; speedup 1.0000x reference)
//
#include <hip/hip_runtime.h>
#include <math.h>

#define B_N 512
#define D_N 768
#define R_N 128
#define ALPHA 2.0f
#define BETA 50.0f
#define BASE 0.5f
#define EPS_M 0.1f

typedef __attribute__((ext_vector_type(4))) float f32x4;
typedef __attribute__((ext_vector_type(8))) short s16x8;

static __device__ inline unsigned short f2bf(float f) {
    union { float f; unsigned u; } v; v.f = f;
    unsigned u = v.u;
    return (unsigned short)((u + 0x7FFFu + ((u >> 16) & 1u)) >> 16);  // RNE
}

static __device__ inline void gload16(const float* g, float* l) {
    __builtin_amdgcn_global_load_lds(
        (const __attribute__((address_space(1))) void*)g,
        (__attribute__((address_space(3))) void*)l, 16, 0, 0);
}

// ============ Kernel 1: grouped matvec t[b] = M[re_id[b]] @ x[b] ============
// grid (128 relations, 12 tiles of 64 rows), block 256 (4 waves), 2 blocks/CU.
// M staged f32 via global_load_lds (double-buffered, source-XOR-swizzled);
// members bf16 in LDS (frag-major); mfma_f32_16x16x32_bf16: 16 rows x 16 members.
__global__ __launch_bounds__(256, 2) void k_matvec(
    const float* __restrict__ transform, const float* __restrict__ cui0,
    const int* __restrict__ re_id, float* __restrict__ t_out,
    int* __restrict__ sync) {
    __shared__ float Mb[2][64 * 96];          // 2 x 24KB; [row][96] linear, content XOR-swz per 16B granule
    __shared__ unsigned short Xb[96 * 16 * 8];// 24KB; granule L = g*16 + m, 8 bf16 each
    __shared__ int mem_s[B_N];
    __shared__ int cnt_s;

    const int tid = threadIdx.x;
    const int r = blockIdx.x;
    const int tile = blockIdx.y * 64;
    if (r == 0 && blockIdx.y == 0 && tid == 0) { sync[0] = 0; sync[1] = 0; }

    // ---- fused bucket scan (no vmem in flight yet -> __syncthreads is free) ----
    if (tid == 0) cnt_s = 0;
    __syncthreads();
    {
        int a = re_id[tid], b2 = re_id[tid + 256];
        if (a == r) { int k = atomicAdd(&cnt_s, 1); mem_s[k] = tid; }
        if (b2 == r) { int k = atomicAdd(&cnt_s, 1); mem_s[k] = tid + 256; }
    }
    __syncthreads();
    const int n = cnt_s;
    if (n == 0) return;

    const int lane = tid & 63;
    const int w = tid >> 6;
    const int l15 = lane & 15;
    const int lh = lane >> 4;
    const int rbase = (w * 16 + l15) * 24;  // granule base of this lane's M row
    const int r7 = l15 & 7;

    const float* Mrel = transform + (size_t)r * (D_N * D_N) + (size_t)tile * D_N;
    const int nmc = (n + 15) >> 4;

    for (int mc = 0; mc < nmc; ++mc) {
        // ---- convert up to 16 member x-vectors to bf16 LDS (frag-major) ----
        {
            int m = tid & 15, j = tid >> 4;
            int bi = mc * 16 + m;
            int bmem = (bi < n) ? mem_s[bi] : -1;
            const float* xs = cui0 + (size_t)(bmem < 0 ? 0 : bmem) * D_N;
            s16x8* Xg = (s16x8*)Xb;
#pragma unroll
            for (int it = 0; it < 6; ++it) {
                int g = j + 16 * it;   // 0..95 -> k = 8g
                s16x8 o = {0, 0, 0, 0, 0, 0, 0, 0};
                if (bmem >= 0) {
                    float4 u0 = *(const float4*)(xs + g * 8);
                    float4 u1 = *(const float4*)(xs + g * 8 + 4);
                    o[0] = (short)f2bf(u0.x); o[1] = (short)f2bf(u0.y);
                    o[2] = (short)f2bf(u0.z); o[3] = (short)f2bf(u0.w);
                    o[4] = (short)f2bf(u1.x); o[5] = (short)f2bf(u1.y);
                    o[6] = (short)f2bf(u1.z); o[7] = (short)f2bf(u1.w);
                }
                Xg[g * 16 + m] = o;
            }
        }
        // ---- stage chunk 0, drain, barrier ----
        {
#pragma unroll
            for (int c = 0; c < 6; ++c) {
                int H = c * 256 + tid;
                int row = H / 24;
                int gp = H - row * 24;
                int g = gp ^ (row & 7);
                gload16(Mrel + row * D_N + g * 4, &Mb[0][0] + (c * 256 + (tid & 192)) * 4);
            }
        }
        asm volatile("s_waitcnt vmcnt(0) lgkmcnt(0)" ::: "memory");
        __builtin_amdgcn_s_barrier();
        __builtin_amdgcn_sched_barrier(0);

        f32x4 acc0 = {0.f, 0.f, 0.f, 0.f};
        f32x4 acc1 = {0.f, 0.f, 0.f, 0.f};
#pragma unroll
        for (int kc = 0; kc < 8; ++kc) {
            if (kc < 7) {  // issue next chunk into the other buffer
                float* nb = (((kc + 1) & 1) ? &Mb[1][0] : &Mb[0][0]);
#pragma unroll
                for (int c = 0; c < 6; ++c) {
                    int H = c * 256 + tid;
                    int row = H / 24;
                    int gp = H - row * 24;
                    int g = gp ^ (row & 7);
                    gload16(Mrel + row * D_N + (kc + 1) * 96 + g * 4,
                            nb + (c * 256 + (tid & 192)) * 4);
                }
            }
            const f32x4* Mg = (const f32x4*)((kc & 1) ? &Mb[1][0] : &Mb[0][0]);
            const s16x8* Xg = (const s16x8*)Xb;
#pragma unroll
            for (int sl = 0; sl < 3; ++sl) {
                int g0 = sl * 8 + 2 * lh;
                f32x4 A0 = Mg[rbase + (g0 ^ r7)];
                f32x4 A1 = Mg[rbase + ((g0 + 1) ^ r7)];
                s16x8 bfrag = Xg[(((kc * 3 + sl) * 4) + lh) * 16 + l15];
                s16x8 af;
                af[0] = (short)f2bf(A0[0]); af[1] = (short)f2bf(A0[1]);
                af[2] = (short)f2bf(A0[2]); af[3] = (short)f2bf(A0[3]);
                af[4] = (short)f2bf(A1[0]); af[5] = (short)f2bf(A1[1]);
                af[6] = (short)f2bf(A1[2]); af[7] = (short)f2bf(A1[3]);
                if (((kc * 3 + sl) & 1) == 0)
                    acc0 = __builtin_amdgcn_mfma_f32_16x16x32_bf16(af, bfrag, acc0, 0, 0, 0);
                else
                    acc1 = __builtin_amdgcn_mfma_f32_16x16x32_bf16(af, bfrag, acc1, 0, 0, 0);
            }
            asm volatile("s_waitcnt vmcnt(0) lgkmcnt(0)" ::: "memory");
            __builtin_amdgcn_s_barrier();
            __builtin_amdgcn_sched_barrier(0);
        }
        // ---- store: D col = member = lane&15, row = lh*4+p [m89-verified] ----
        {
            int bi = mc * 16 + l15;
            if (bi < n) {
                int bmem = mem_s[bi];
                int grow = tile + w * 16 + lh * 4;
                float4 o;
                o.x = acc0[0] + acc1[0];
                o.y = acc0[1] + acc1[1];
                o.z = acc0[2] + acc1[2];
                o.w = acc0[3] + acc1[3];
                *(float4*)(t_out + (size_t)bmem * D_N + grow) = o;
            }
        }
    }
}

// ============ grid sync helper (256 co-resident blocks) ============
static __device__ inline void gsync(int* c, int target) {
    __syncthreads();
    if (threadIdx.x == 0) {
        __threadfence();
        __hip_atomic_fetch_add(c, 1, __ATOMIC_ACQ_REL, __HIP_MEMORY_SCOPE_AGENT);
        while (__hip_atomic_load(c, __ATOMIC_ACQUIRE, __HIP_MEMORY_SCOPE_AGENT) < target) {
            __builtin_amdgcn_s_sleep(8);
        }
        __threadfence();
    }
    __syncthreads();
}

// ============ Kernel 2: fused tail = norm+bf16 -> gemm -> loss -> mean ======
// grid 256, block 256.
__global__ __launch_bounds__(256) void k_tail(
    const float* __restrict__ t_in, const float* __restrict__ cui1,
    const int* __restrict__ lab, unsigned short* __restrict__ tn,
    unsigned short* __restrict__ cn, float* __restrict__ mat,
    float* __restrict__ row_loss, int* __restrict__ sync,
    float* __restrict__ out) {
    __shared__ float tmp[4];
    __shared__ int is_last;
    const int bid = blockIdx.x;
    const int tid = threadIdx.x;
    const int lane = tid & 63, w = tid >> 6;

    // ---- P1: normalize + bf16 (1024 rows, one per wave) ----
    {
        int gw = bid * 4 + w;
        bool isA = gw < B_N;
        const float* src = isA ? (t_in + (size_t)gw * D_N)
                               : (cui1 + (size_t)(gw - B_N) * D_N);
        unsigned short* dst = isA ? (tn + (size_t)gw * D_N)
                                  : (cn + (size_t)(gw - B_N) * D_N);
        const float4* s4 = (const float4*)src;
        float4 v[3];
        float ss = 0.f;
#pragma unroll
        for (int c = 0; c < 3; ++c) {
            v[c] = s4[c * 64 + lane];
            ss += v[c].x * v[c].x + v[c].y * v[c].y + v[c].z * v[c].z + v[c].w * v[c].w;
        }
#pragma unroll
        for (int off = 32; off > 0; off >>= 1) ss += __shfl_xor(ss, off, 64);
        float inv = 1.0f / fmaxf(sqrtf(ss), 1e-12f);
        ushort4* d4 = (ushort4*)dst;
#pragma unroll
        for (int c = 0; c < 3; ++c) {
            ushort4 o;
            o.x = f2bf(v[c].x * inv); o.y = f2bf(v[c].y * inv);
            o.z = f2bf(v[c].z * inv); o.w = f2bf(v[c].w * inv);
            d4[c * 64 + lane] = o;
        }
    }
    gsync(sync, 256);

    // ---- P2: LDS-free bf16 MFMA gemm, 32x32 tile per block ----
    {
        int bx = bid & 15, by = bid >> 4;
        int wr = w >> 1, wc = w & 1;
        int l15 = lane & 15, lh = lane >> 4;
        int arow = by * 32 + wr * 16 + l15;
        int bcol = bx * 32 + wc * 16 + l15;
        const s16x8* ap = (const s16x8*)(tn + (size_t)arow * D_N);
        const s16x8* bp = (const s16x8*)(cn + (size_t)bcol * D_N);
        f32x4 acc0 = {0.f, 0.f, 0.f, 0.f};
        f32x4 acc1 = {0.f, 0.f, 0.f, 0.f};
#pragma unroll
        for (int ks = 0; ks < 24; ks += 2) {
            s16x8 a0 = ap[ks * 4 + lh];
            s16x8 b0 = bp[ks * 4 + lh];
            s16x8 a1 = ap[ks * 4 + 4 + lh];
            s16x8 b1 = bp[ks * 4 + 4 + lh];
            acc0 = __builtin_amdgcn_mfma_f32_16x16x32_bf16(a0, b0, acc0, 0, 0, 0);
            acc1 = __builtin_amdgcn_mfma_f32_16x16x32_bf16(a1, b1, acc1, 0, 0, 0);
        }
        int grow = by * 32 + wr * 16 + lh * 4;
#pragma unroll
        for (int p = 0; p < 4; ++p)
            mat[(size_t)(grow + p) * B_N + bcol] = acc0[p] + acc1[p];
    }
    gsync(sync, 512);

    // ---- P3: miner + MS loss for rows 2*bid, 2*bid+1; last block -> mean ----
    for (int rr = 0; rr < 2; ++rr) {
        int r = bid * 2 + rr;
        int lr = lab[r];
        const float* mrow = mat + (size_t)r * B_N;

        float v0 = mrow[tid], v1 = mrow[tid + 256];
        bool m0 = (lab[tid] == lr), m1 = (lab[tid + 256] == lr);

        float mx = -INFINITY, mn = INFINITY;
        if (m0) mn = v0; else mx = v0;
        if (m1) mn = fminf(mn, v1); else mx = fmaxf(mx, v1);

#pragma unroll
        for (int off = 32; off > 0; off >>= 1) mx = fmaxf(mx, __shfl_xor(mx, off, 64));
        if (lane == 0) tmp[w] = mx;
        __syncthreads();
        float max_neg = fmaxf(fmaxf(tmp[0], tmp[1]), fmaxf(tmp[2], tmp[3]));
        __syncthreads();

#pragma unroll
        for (int off = 32; off > 0; off >>= 1) mn = fminf(mn, __shfl_xor(mn, off, 64));
        if (lane == 0) tmp[w] = mn;
        __syncthreads();
        float min_pos = fminf(fminf(tmp[0], tmp[1]), fminf(tmp[2], tmp[3]));
        __syncthreads();

        float psum = 0.f, nsum = 0.f;
        if (m0 && (v0 - EPS_M < max_neg)) psum += expf(ALPHA * (BASE - v0));
        if (!m0 && (v0 + EPS_M > min_pos)) nsum += expf(BETA * (v0 - BASE));
        if (m1 && (v1 - EPS_M < max_neg)) psum += expf(ALPHA * (BASE - v1));
        if (!m1 && (v1 + EPS_M > min_pos)) nsum += expf(BETA * (v1 - BASE));

#pragma unroll
        for (int off = 32; off > 0; off >>= 1) psum += __shfl_xor(psum, off, 64);
        if (lane == 0) tmp[w] = psum;
        __syncthreads();
        float ps = tmp[0] + tmp[1] + tmp[2] + tmp[3];
        __syncthreads();

#pragma unroll
        for (int off = 32; off > 0; off >>= 1) nsum += __shfl_xor(nsum, off, 64);
        if (lane == 0) tmp[w] = nsum;
        __syncthreads();
        float ns = tmp[0] + tmp[1] + tmp[2] + tmp[3];

        if (tid == 0)
            row_loss[r] = (1.0f / ALPHA) * log1pf(ps) + (1.0f / BETA) * log1pf(ns);
        __syncthreads();
    }

    if (tid == 0) {
        __threadfence();
        int prev = __hip_atomic_fetch_add(&sync[1], 1, __ATOMIC_ACQ_REL, __HIP_MEMORY_SCOPE_AGENT);
        is_last = (prev == 255) ? 1 : 0;
    }
    __syncthreads();
    if (is_last) {
        __threadfence();
        float v = row_loss[tid] + row_loss[tid + 256];
#pragma unroll
        for (int off = 32; off > 0; off >>= 1) v += __shfl_xor(v, off, 64);
        if (lane == 0) tmp[w] = v;
        __syncthreads();
        if (tid == 0)
            out[0] = (tmp[0] + tmp[1] + tmp[2] + tmp[3]) / (float)B_N;
    }
}

extern "C" void kernel_launch(void* const* d_in, const int* in_sizes, int n_in,
                              void* d_out, int out_size, void* d_ws, size_t ws_size,
                              hipStream_t stream) {
    const float* cui0      = (const float*)d_in[0];
    const float* cui1      = (const float*)d_in[1];
    const int*   re_id     = (const int*)d_in[2];
    const int*   lab1      = (const int*)d_in[4];
    const float* transform = (const float*)d_in[5];
    float* out = (float*)d_out;

    char* wsb = (char*)d_ws;
    unsigned short* tn = (unsigned short*)wsb;              // 512*768 bf16 = 786432 B
    unsigned short* cn = (unsigned short*)(wsb + 786432);   // 786432 B
    float* t        = (float*)(wsb + 1572864);              // 512*768 f32 = 1572864 B
    float* mat      = (float*)(wsb + 3145728);              // 512*512 f32 = 1048576 B
    float* row_loss = (float*)(wsb + 4194304);              // 2048 B
    int*   sync     = (int*)(wsb + 4196352);                // 16 B

    hipLaunchKernelGGL(k_matvec, dim3(R_N, 12), dim3(256), 0, stream,
                       transform, cui0, re_id, t, sync);
    hipLaunchKernelGGL(k_tail, dim3(256), dim3(256), 0, stream,
                       t, cui1, lab1, tn, cn, mat, row_loss, sync, out);
}